// Round 3
// baseline (639.932 us; speedup 1.0000x reference)
//
#include <hip/hip_runtime.h>
#include <hip/hip_bf16.h>

#define B_ 256
#define T_ 512
#define I_ 256
#define H_ 256

typedef float  f32x4  __attribute__((ext_vector_type(4)));
typedef short  bf16x8 __attribute__((ext_vector_type(8)));
typedef short  s16x4  __attribute__((ext_vector_type(4)));
typedef _Float16 f16x2 __attribute__((ext_vector_type(2)));
typedef _Float16 f16x8 __attribute__((ext_vector_type(8)));

// f32 -> bf16 round-to-nearest-even
static __device__ __forceinline__ short f2bf(float f) {
  unsigned u = __builtin_bit_cast(unsigned, f);
  u += 0x7FFFu + ((u >> 16) & 1u);
  return (short)(u >> 16);
}

// ---------------- kernel 0: W_x f32 -> bf16 (into ws) ----------------
__global__ __launch_bounds__(256) void wx_to_bf16(const float* __restrict__ wx,
                                                  short* __restrict__ wb) {
  int i = blockIdx.x * 256 + threadIdx.x;           // each handles 4 elems
  f32x4 v = ((const f32x4*)wx)[i];
  s16x4 o;
  o[0] = f2bf(v[0]); o[1] = f2bf(v[1]); o[2] = f2bf(v[2]); o[3] = f2bf(v[3]);
  ((s16x4*)wb)[i] = o;
}

// ---------------- kernel 1: Xp = x @ W_x^T  (MFMA bf16) ----------------
// x: [131072, 256] f32 row-major; W: [h, i] (h*256+i); Xp: [131072, 256] f32.
// Block = 256 thr (4 waves). Wave: M=16 rows, N=256 (16 n-tiles), K=256.
template <bool PRE>
__global__ __launch_bounds__(256) void xproj(const float* __restrict__ x,
                                             const float* __restrict__ wxf,
                                             const short* __restrict__ wxb,
                                             float* __restrict__ xp) {
  const int l  = threadIdx.x & 63;
  const int w  = threadIdx.x >> 6;
  const int m0 = (blockIdx.x * 4 + w) * 16;
  const int lr = l & 15;          // row within A-frag / col within D
  const int g  = l >> 4;          // k-group
  f32x4 acc[16];
#pragma unroll
  for (int nt = 0; nt < 16; ++nt) acc[nt] = f32x4{0.f, 0.f, 0.f, 0.f};

  for (int kk = 0; kk < 8; ++kk) {
    const int k = kk * 32 + g * 8;
    // A fragment: lane holds x[m0+lr][k..k+8)
    const f32x4* xa = (const f32x4*)(x + (size_t)(m0 + lr) * I_ + k);
    f32x4 a0 = xa[0], a1 = xa[1];
    bf16x8 af;
    af[0] = f2bf(a0[0]); af[1] = f2bf(a0[1]); af[2] = f2bf(a0[2]); af[3] = f2bf(a0[3]);
    af[4] = f2bf(a1[0]); af[5] = f2bf(a1[1]); af[6] = f2bf(a1[2]); af[7] = f2bf(a1[3]);
#pragma unroll
    for (int nt = 0; nt < 16; ++nt) {
      const int n = nt * 16 + lr;
      bf16x8 bf;
      if (PRE) {
        bf = *(const bf16x8*)(wxb + (size_t)n * I_ + k);
      } else {
        const f32x4* wa = (const f32x4*)(wxf + (size_t)n * I_ + k);
        f32x4 b0 = wa[0], b1 = wa[1];
        bf[0] = f2bf(b0[0]); bf[1] = f2bf(b0[1]); bf[2] = f2bf(b0[2]); bf[3] = f2bf(b0[3]);
        bf[4] = f2bf(b1[0]); bf[5] = f2bf(b1[1]); bf[6] = f2bf(b1[2]); bf[7] = f2bf(b1[3]);
      }
      acc[nt] = __builtin_amdgcn_mfma_f32_16x16x32_bf16(af, bf, acc[nt], 0, 0, 0);
    }
  }
  // D layout (measured): row = (l>>4)*4 + r, col = l&15
#pragma unroll
  for (int nt = 0; nt < 16; ++nt) {
#pragma unroll
    for (int r = 0; r < 4; ++r) {
      const int rr = m0 + g * 4 + r;
      xp[(size_t)rr * H_ + nt * 16 + lr] = acc[nt][r];
    }
  }
}

// ---------------- kernel 2: recurrence v2 ----------------
// One block per batch row. 1024 threads: thread (h = tid>>2, kh = tid&3) owns
// W_h[h][kh*64 .. +64) in 32 f16x2 regs. In-wave butterfly reduce (threads of
// the same h are adjacent lanes), double-buffered h in LDS -> ONE barrier/step.
__global__ __launch_bounds__(1024) void rnn_rec2(const float* __restrict__ whf,
                                                 const float* __restrict__ bias_g,
                                                 float* __restrict__ io) {
  __shared__ __align__(16) _Float16 hb[2][H_];
  const int tid = threadIdx.x;
  const int h   = tid >> 2;
  const int kh  = tid & 3;
  const size_t base = (size_t)blockIdx.x * T_ * H_;

  // weights: W_h[h][kh*64 + 2k, 2k+1] -> wr[k]
  f16x2 wr[32];
  const f32x4* wrow = (const f32x4*)(whf + (size_t)h * H_ + kh * 64);
#pragma unroll
  for (int c = 0; c < 16; ++c) {
    f32x4 v = wrow[c];
    wr[2 * c]     = f16x2{(_Float16)v[0], (_Float16)v[1]};
    wr[2 * c + 1] = f16x2{(_Float16)v[2], (_Float16)v[3]};
  }
  const float bias = bias_g[h];
  if (tid < H_) hb[0][tid] = (_Float16)0.f;
  float xp_cur = io[base + h];                      // t = 0
  float xp_nxt = io[base + H_ + h];                 // t = 1
  __syncthreads();

  int cur = 0;
  for (int t = 0; t < T_; ++t) {
    float xp_fut = 0.f;
    if (t + 2 < T_) xp_fut = io[base + (size_t)(t + 2) * H_ + h];

    // 8 broadcast b128 reads; chunk order staggered by kh so the 4 distinct
    // addresses per instr hit disjoint bank groups (kh stride = 8 banks).
    float a0 = 0.f, a1 = 0.f, a2 = 0.f, a3 = 0.f;
    const f16x8* hp = (const f16x8*)hb[cur];
#pragma unroll
    for (int c = 0; c < 8; ++c) {
      const int cc = (c + kh * 2) & 7;
      f16x8 hv = hp[kh * 8 + cc];
      a0 = __builtin_amdgcn_fdot2(wr[4 * cc + 0], __builtin_shufflevector(hv, hv, 0, 1), a0, false);
      a1 = __builtin_amdgcn_fdot2(wr[4 * cc + 1], __builtin_shufflevector(hv, hv, 2, 3), a1, false);
      a2 = __builtin_amdgcn_fdot2(wr[4 * cc + 2], __builtin_shufflevector(hv, hv, 4, 5), a2, false);
      a3 = __builtin_amdgcn_fdot2(wr[4 * cc + 3], __builtin_shufflevector(hv, hv, 6, 7), a3, false);
    }
    float s = (a0 + a1) + (a2 + a3);
    s += __shfl_xor(s, 1);
    s += __shfl_xor(s, 2);                          // all 4 lanes hold full dot

    float y = s + xp_cur + bias;
    y = fminf(fmaxf(y, -15.f), 15.f);
    float e = __expf(2.f * y);
    float hv2 = (e - 1.f) / (e + 1.f);              // tanh(y)
    if (kh == 0) {
      io[base + (size_t)t * H_ + h] = hv2;          // 16 lanes -> 64B contiguous
      hb[cur ^ 1][h] = (_Float16)hv2;
    }
    __syncthreads();                                // single barrier per step
    cur ^= 1;
    xp_cur = xp_nxt;
    xp_nxt = xp_fut;
  }
}

extern "C" void kernel_launch(void* const* d_in, const int* in_sizes, int n_in,
                              void* d_out, int out_size, void* d_ws, size_t ws_size,
                              hipStream_t stream) {
  const float* x  = (const float*)d_in[0];
  const float* wx = (const float*)d_in[1];
  const float* wh = (const float*)d_in[2];
  const float* b  = (const float*)d_in[3];
  float* out = (float*)d_out;

  const size_t wb_bytes = (size_t)I_ * H_ * sizeof(short);
  if (ws_size >= wb_bytes) {
    short* wb = (short*)d_ws;
    wx_to_bf16<<<64, 256, 0, stream>>>(wx, wb);
    xproj<true><<<2048, 256, 0, stream>>>(x, wx, wb, out);
  } else {
    xproj<false><<<2048, 256, 0, stream>>>(x, wx, nullptr, out);
  }
  rnn_rec2<<<B_, 1024, 0, stream>>>(wh, b, out);
}

// Round 5
// 523.626 us; speedup vs baseline: 1.2221x; 1.2221x over previous
//
#include <hip/hip_runtime.h>
#include <hip/hip_bf16.h>

#define B_ 256
#define T_ 512
#define I_ 256
#define H_ 256

typedef float  f32x4  __attribute__((ext_vector_type(4)));
typedef short  bf16x8 __attribute__((ext_vector_type(8)));
typedef short  s16x4  __attribute__((ext_vector_type(4)));
typedef _Float16 f16x2 __attribute__((ext_vector_type(2)));
typedef _Float16 f16x8 __attribute__((ext_vector_type(8)));

// f32 -> bf16 round-to-nearest-even
static __device__ __forceinline__ short f2bf(float f) {
  unsigned u = __builtin_bit_cast(unsigned, f);
  u += 0x7FFFu + ((u >> 16) & 1u);
  return (short)(u >> 16);
}

// ---------------- kernel 0: W_x f32 -> bf16 (into ws) ----------------
__global__ __launch_bounds__(256) void wx_to_bf16(const float* __restrict__ wx,
                                                  short* __restrict__ wb) {
  int i = blockIdx.x * 256 + threadIdx.x;           // each handles 4 elems
  f32x4 v = ((const f32x4*)wx)[i];
  s16x4 o;
  o[0] = f2bf(v[0]); o[1] = f2bf(v[1]); o[2] = f2bf(v[2]); o[3] = f2bf(v[3]);
  ((s16x4*)wb)[i] = o;
}

// ---------------- kernel 1: Xp = x @ W_x^T  (MFMA bf16) ----------------
// x: [131072, 256] f32 row-major; W: [h, i] (h*256+i); Xp: [131072, 256] f32.
// Block = 256 thr (4 waves). Wave: M=16 rows, N=256 (16 n-tiles), K=256.
template <bool PRE>
__global__ __launch_bounds__(256) void xproj(const float* __restrict__ x,
                                             const float* __restrict__ wxf,
                                             const short* __restrict__ wxb,
                                             float* __restrict__ xp) {
  const int l  = threadIdx.x & 63;
  const int w  = threadIdx.x >> 6;
  const int m0 = (blockIdx.x * 4 + w) * 16;
  const int lr = l & 15;          // row within A-frag / col within D
  const int g  = l >> 4;          // k-group
  f32x4 acc[16];
#pragma unroll
  for (int nt = 0; nt < 16; ++nt) acc[nt] = f32x4{0.f, 0.f, 0.f, 0.f};

  for (int kk = 0; kk < 8; ++kk) {
    const int k = kk * 32 + g * 8;
    // A fragment: lane holds x[m0+lr][k..k+8)
    const f32x4* xa = (const f32x4*)(x + (size_t)(m0 + lr) * I_ + k);
    f32x4 a0 = xa[0], a1 = xa[1];
    bf16x8 af;
    af[0] = f2bf(a0[0]); af[1] = f2bf(a0[1]); af[2] = f2bf(a0[2]); af[3] = f2bf(a0[3]);
    af[4] = f2bf(a1[0]); af[5] = f2bf(a1[1]); af[6] = f2bf(a1[2]); af[7] = f2bf(a1[3]);
#pragma unroll
    for (int nt = 0; nt < 16; ++nt) {
      const int n = nt * 16 + lr;
      bf16x8 bf;
      if (PRE) {
        bf = *(const bf16x8*)(wxb + (size_t)n * I_ + k);
      } else {
        const f32x4* wa = (const f32x4*)(wxf + (size_t)n * I_ + k);
        f32x4 b0 = wa[0], b1 = wa[1];
        bf[0] = f2bf(b0[0]); bf[1] = f2bf(b0[1]); bf[2] = f2bf(b0[2]); bf[3] = f2bf(b0[3]);
        bf[4] = f2bf(b1[0]); bf[5] = f2bf(b1[1]); bf[6] = f2bf(b1[2]); bf[7] = f2bf(b1[3]);
      }
      acc[nt] = __builtin_amdgcn_mfma_f32_16x16x32_bf16(af, bf, acc[nt], 0, 0, 0);
    }
  }
  // D layout (measured): row = (l>>4)*4 + r, col = l&15
#pragma unroll
  for (int nt = 0; nt < 16; ++nt) {
#pragma unroll
    for (int r = 0; r < 4; ++r) {
      const int rr = m0 + g * 4 + r;
      xp[(size_t)rr * H_ + nt * 16 + lr] = acc[nt][r];
    }
  }
}

// ---------------- kernel 2: recurrence v3 ----------------
// One block per batch row, 512 threads (8 waves). Thread (h = tid>>1, kh = tid&1)
// owns W_h[h][kh*128 .. +128) in 64 f16x2 regs (ALL indices compile-time —
// v2's runtime-staggered wr[] index spilled the weight array to scratch).
// Reduce partner is the adjacent lane -> one shfl_xor, one barrier per step.
__global__ __launch_bounds__(512) void rnn_rec3(const float* __restrict__ whf,
                                                const float* __restrict__ bias_g,
                                                float* __restrict__ io) {
  __shared__ __align__(16) _Float16 hb[2][H_];
  const int tid = threadIdx.x;
  const int h   = tid >> 1;
  const int kh  = tid & 1;
  const size_t base = (size_t)blockIdx.x * T_ * H_;

  // weights: W_h[h][kh*128 + 2k, 2k+1] -> wr[k]
  f16x2 wr[64];
  const f32x4* wrow = (const f32x4*)(whf + (size_t)h * H_ + kh * 128);
#pragma unroll
  for (int c = 0; c < 32; ++c) {
    f32x4 v = wrow[c];
    wr[2 * c]     = f16x2{(_Float16)v[0], (_Float16)v[1]};
    wr[2 * c + 1] = f16x2{(_Float16)v[2], (_Float16)v[3]};
  }
  const float bias = bias_g[h];
  if (tid < H_) hb[0][tid] = (_Float16)0.f;
  float xp_cur = io[base + h];                      // t = 0
  float xp_nxt = io[base + H_ + h];                 // t = 1
  __syncthreads();

  int cur = 0;
  for (int t = 0; t < T_; ++t) {
    float xp_fut = 0.f;
    if (t + 2 < T_) xp_fut = io[base + (size_t)(t + 2) * H_ + h];

    // 16 broadcast b128 reads (2 distinct addrs per wave-instr), static order.
    float a0 = 0.f, a1 = 0.f, a2 = 0.f, a3 = 0.f;
    const f16x8* hp = ((const f16x8*)hb[cur]) + kh * 16;
#pragma unroll
    for (int c = 0; c < 16; ++c) {
      f16x8 hv = hp[c];
      a0 = __builtin_amdgcn_fdot2(wr[4 * c + 0], __builtin_shufflevector(hv, hv, 0, 1), a0, false);
      a1 = __builtin_amdgcn_fdot2(wr[4 * c + 1], __builtin_shufflevector(hv, hv, 2, 3), a1, false);
      a2 = __builtin_amdgcn_fdot2(wr[4 * c + 2], __builtin_shufflevector(hv, hv, 4, 5), a2, false);
      a3 = __builtin_amdgcn_fdot2(wr[4 * c + 3], __builtin_shufflevector(hv, hv, 6, 7), a3, false);
    }
    float s = (a0 + a1) + (a2 + a3);
    s += __shfl_xor(s, 1);                          // partner lane -> full dot

    float y = s + xp_cur + bias;
    // tanh(y) = 1 - 2/(1 + e^{2y}); rcp(inf)=0 handles saturation, no clamp.
    float e = __expf(2.f * y);
    float hv2 = 1.f - 2.f * __builtin_amdgcn_rcpf(1.f + e);
    if (kh == 0) {
      io[base + (size_t)t * H_ + h] = hv2;          // 32 lanes -> 128B contiguous
      hb[cur ^ 1][h] = (_Float16)hv2;
    }
    __syncthreads();                                // single barrier per step
    cur ^= 1;
    xp_cur = xp_nxt;
    xp_nxt = xp_fut;
  }
}

extern "C" void kernel_launch(void* const* d_in, const int* in_sizes, int n_in,
                              void* d_out, int out_size, void* d_ws, size_t ws_size,
                              hipStream_t stream) {
  const float* x  = (const float*)d_in[0];
  const float* wx = (const float*)d_in[1];
  const float* wh = (const float*)d_in[2];
  const float* b  = (const float*)d_in[3];
  float* out = (float*)d_out;

  const size_t wb_bytes = (size_t)I_ * H_ * sizeof(short);
  if (ws_size >= wb_bytes) {
    short* wb = (short*)d_ws;
    wx_to_bf16<<<64, 256, 0, stream>>>(wx, wb);
    xproj<true><<<2048, 256, 0, stream>>>(x, wx, wb, out);
  } else {
    xproj<false><<<2048, 256, 0, stream>>>(x, wx, nullptr, out);
  }
  rnn_rec3<<<B_, 512, 0, stream>>>(wh, b, out);
}